// Round 2
// baseline (56.863 us; speedup 1.0000x reference)
//
#include <hip/hip_runtime.h>
#include <math.h>

#define EPS_COS 1e-8f
#define EPS_ADD 1e-12f

// B=256 batches, one block per batch (grid = 256 = #CUs). N=4096, M=64, S=3.
// Block = 1024 threads = 16 waves.
// Main pass mapping: 4 lanes per row. Lane l handles row (l>>2) of its wave's
// 16-row group, element-quarter q=(l&3): float4 indices {q, q+4, q+8, q+12}.
// Each load instruction is sector-perfect: 64 lanes cover 64 fully-used 64-B
// chunks. Row reduction = 2 shfl_xor steps (vs 4 for a 16-lane mapping).

constexpr int NTHREADS = 1024;
constexpr int NWAVES   = NTHREADS / 64;   // 16
constexpr int MAX_N    = 4096;

__global__ __launch_bounds__(NTHREADS, 1) void ntm_attention_kernel(
    const float* __restrict__ beta,    // [B,1]
    const float* __restrict__ kappa,   // [B,64]
    const float* __restrict__ gamma,   // [B,1]
    const float* __restrict__ g,       // [B,1]
    const float* __restrict__ s,       // [B,S]
    const float* __restrict__ w_prev,  // [B,N]
    const float* __restrict__ mem,     // [B,N,64]
    float* __restrict__ out,           // [B,N]
    int N, int S)
{
    const int b    = blockIdx.x;
    const int tid  = threadIdx.x;
    const int lane = tid & 63;
    const int wave = tid >> 6;
    const int q    = lane & 3;    // element-quarter within the row
    const int r16  = lane >> 2;   // row within the wave's 16-row group

    __shared__ float t_sh[MAX_N];    // scores -> exp -> sharpened
    __shared__ float w_sh[MAX_N];    // interpolated weights (for shift)
    __shared__ float wp_sh[MAX_N];   // prefetched w_prev
    __shared__ float red[NWAVES];

    // ---- prefetch w_prev into LDS (overlaps with the main memory stream) ----
    {
        const float4* wp = reinterpret_cast<const float4*>(w_prev + (size_t)b * N);
        float4* dst = reinterpret_cast<float4*>(wp_sh);
        for (int i = tid; i < (N >> 2); i += NTHREADS) dst[i] = wp[i];
    }

    // ---- kappa fragment: lane holds float4s {q, q+4, q+8, q+12} (+eps) ----
    float4 kv[4];
    {
        const float4* kp = reinterpret_cast<const float4*>(kappa + (size_t)b * 64);
#pragma unroll
        for (int j = 0; j < 4; ++j) {
            kv[j] = kp[q + 4 * j];
            kv[j].x += EPS_ADD; kv[j].y += EPS_ADD;
            kv[j].z += EPS_ADD; kv[j].w += EPS_ADD;
        }
    }
    float nb2 = 0.0f;
#pragma unroll
    for (int j = 0; j < 4; ++j)
        nb2 += kv[j].x * kv[j].x + kv[j].y * kv[j].y + kv[j].z * kv[j].z + kv[j].w * kv[j].w;
    nb2 += __shfl_xor(nb2, 1);
    nb2 += __shfl_xor(nb2, 2);
    const float nb = fmaxf(sqrtf(nb2), EPS_COS);
    const float bv_over_nb = beta[b] / nb;

    // ---- main pass: 16 waves x 16 rows = 256 rows per iteration ----
    const float4* mp = reinterpret_cast<const float4*>(mem + (size_t)b * N * 64);
    const int nIter = N >> 8;   // 16 for N=4096 (assumes N % 256 == 0)
    float tmax = -INFINITY;

    int row0 = wave * 16 + r16;
    const float4* p = mp + (size_t)row0 * 16 + q;
    float4 a0 = p[0], a1 = p[4], a2 = p[8], a3 = p[12];

    for (int it = 0; it < nIter; ++it) {
        const float4 c0 = a0, c1 = a1, c2 = a2, c3 = a3;
        if (it + 1 < nIter) {
            const float4* pn = p + (size_t)(it + 1) * 4096;   // 256 rows * 16 f4
            a0 = pn[0]; a1 = pn[4]; a2 = pn[8]; a3 = pn[12];
        }

        float d = 0.0f, n2 = 0.0f;
        d += c0.x * kv[0].x + c0.y * kv[0].y + c0.z * kv[0].z + c0.w * kv[0].w;
        d += c1.x * kv[1].x + c1.y * kv[1].y + c1.z * kv[1].z + c1.w * kv[1].w;
        d += c2.x * kv[2].x + c2.y * kv[2].y + c2.z * kv[2].z + c2.w * kv[2].w;
        d += c3.x * kv[3].x + c3.y * kv[3].y + c3.z * kv[3].z + c3.w * kv[3].w;
        n2 += c0.x * c0.x + c0.y * c0.y + c0.z * c0.z + c0.w * c0.w;
        n2 += c1.x * c1.x + c1.y * c1.y + c1.z * c1.z + c1.w * c1.w;
        n2 += c2.x * c2.x + c2.y * c2.y + c2.z * c2.z + c2.w * c2.w;
        n2 += c3.x * c3.x + c3.y * c3.y + c3.z * c3.z + c3.w * c3.w;

        d  += __shfl_xor(d, 1);  d  += __shfl_xor(d, 2);
        n2 += __shfl_xor(n2, 1); n2 += __shfl_xor(n2, 2);

        const float inv_na = rsqrtf(fmaxf(n2, 1e-16f));   // matches max(na,1e-8)
        const float t = bv_over_nb * d * inv_na;
        const int row = row0 + it * 256;
        if (q == 0) t_sh[row] = t;
        tmax = fmaxf(tmax, t);
    }

    // ---- block-wide max ----
#pragma unroll
    for (int m = 1; m < 64; m <<= 1) tmax = fmaxf(tmax, __shfl_xor(tmax, m));
    if (lane == 0) red[wave] = tmax;
    __syncthreads();
    float gmax = red[0];
#pragma unroll
    for (int i = 1; i < NWAVES; ++i) gmax = fmaxf(gmax, red[i]);
    __syncthreads();

    // ---- exp + sum ----
    float lsum = 0.0f;
    for (int i = tid; i < N; i += NTHREADS) {
        const float e = expf(t_sh[i] - gmax);
        t_sh[i] = e;
        lsum += e;
    }
#pragma unroll
    for (int m = 1; m < 64; m <<= 1) lsum += __shfl_xor(lsum, m);
    if (lane == 0) red[wave] = lsum;
    __syncthreads();
    float tot = 0.0f;
#pragma unroll
    for (int i = 0; i < NWAVES; ++i) tot += red[i];
    __syncthreads();

    // ---- w_c = softmax, interpolate with (prefetched) w_prev ----
    const float gv = g[b];
    const float inv_tot = 1.0f / tot;
    for (int i = tid; i < N; i += NTHREADS) {
        const float wc = t_sh[i] * inv_tot;
        w_sh[i] = gv * wc + (1.0f - gv) * wp_sh[i];
    }
    __syncthreads();

    // ---- circular shift + sharpen ----
    const float gam = gamma[b];
    float sv[8];
    const int Sc = (S < 8) ? S : 8;
    for (int j = 0; j < Sc; ++j) sv[j] = s[(size_t)b * S + j];

    float ssum = 0.0f;
    for (int i = tid; i < N; i += NTHREADS) {
        float wh = 0.0f;
        for (int j = 0; j < Sc; ++j) {
            int idx = i + j - 1 + N;
            if (idx >= N) idx -= N;
            if (idx >= N) idx -= N;
            wh += sv[j] * w_sh[idx];
        }
        const float sh = powf(wh, gam);
        t_sh[i] = sh;
        ssum += sh;
    }
#pragma unroll
    for (int m = 1; m < 64; m <<= 1) ssum += __shfl_xor(ssum, m);
    if (lane == 0) red[wave] = ssum;
    __syncthreads();
    float stot = 0.0f;
#pragma unroll
    for (int i = 0; i < NWAVES; ++i) stot += red[i];

    // ---- normalize + write ----
    const float inv_den = 1.0f / (stot + EPS_ADD);
    for (int i = tid; i < N; i += NTHREADS) {
        out[(size_t)b * N + i] = t_sh[i] * inv_den;
    }
}

extern "C" void kernel_launch(void* const* d_in, const int* in_sizes, int n_in,
                              void* d_out, int out_size, void* d_ws, size_t ws_size,
                              hipStream_t stream) {
    const float* beta   = (const float*)d_in[0];
    const float* kappa  = (const float*)d_in[1];
    const float* gamma  = (const float*)d_in[2];
    const float* g      = (const float*)d_in[3];
    const float* s      = (const float*)d_in[4];
    const float* w_prev = (const float*)d_in[5];
    const float* mem    = (const float*)d_in[6];
    float* out          = (float*)d_out;

    const int B = in_sizes[0];            // beta is (B,1)
    const int N = in_sizes[5] / B;        // w_prev is (B,N)
    const int S = in_sizes[4] / B;        // s is (B,S)

    ntm_attention_kernel<<<B, NTHREADS, 0, stream>>>(
        beta, kappa, gamma, g, s, w_prev, mem, out, N, S);
}